// Round 4
// baseline (610.828 us; speedup 1.0000x reference)
//
#include <hip/hip_runtime.h>
#include <hip/hip_fp16.h>

typedef _Float16 f16;
typedef _Float16 f16x8 __attribute__((ext_vector_type(8)));
typedef float f32x4 __attribute__((ext_vector_type(4)));

#define S_LEN 16384
#define DIMM  1280
#define NHEAD 16
#define HDIM  80
#define WIN   64

// ---- workspace layout (bytes) ----
#define OFF_HB   0ULL
#define OFF_WQKV (OFF_HB   + (unsigned long long)S_LEN*DIMM*2)
#define OFF_WP   (OFF_WQKV + (unsigned long long)3*DIMM*DIMM*2)
#define OFF_Q    (OFF_WP   + (unsigned long long)DIMM*DIMM*2)
#define OFF_K    (OFF_Q    + (unsigned long long)S_LEN*DIMM*2)
#define OFF_V    (OFF_K    + (unsigned long long)S_LEN*DIMM*2)
#define OFF_AO   OFF_HB    // aliases Hb (stream-ordered: Hb last read by QKV GEMM)

static __device__ __forceinline__ void async_load16(const f16* g, f16* lds) {
  __builtin_amdgcn_global_load_lds((const __attribute__((address_space(1))) void*)g,
                                   (__attribute__((address_space(3))) void*)lds,
                                   16, 0, 0);
}

// ---------------- fp32 -> fp16 converts ----------------
__global__ void cvt_k(const float* __restrict__ src, f16* __restrict__ dst, int n8) {
  int i = blockIdx.x * 256 + threadIdx.x;
  if (i >= n8) return;
  const f32x4* s = (const f32x4*)src + 2 * (long long)i;
  f32x4 a = s[0], b = s[1];
  f16x8 o;
  #pragma unroll
  for (int j = 0; j < 4; ++j) { o[j] = (f16)a[j]; o[4 + j] = (f16)b[j]; }
  *((f16x8*)dst + (long long)i) = o;
}

__global__ void cvtw_k(const float* __restrict__ w0, const float* __restrict__ w1,
                       const float* __restrict__ w2, const float* __restrict__ w3,
                       f16* __restrict__ dst) {
  int m = blockIdx.y;
  const float* src = m == 0 ? w0 : m == 1 ? w1 : m == 2 ? w2 : w3;
  int i = blockIdx.x * 256 + threadIdx.x;
  const f32x4* s = (const f32x4*)src + 2 * (long long)i;
  f32x4 a = s[0], b = s[1];
  f16x8 o;
  #pragma unroll
  for (int j = 0; j < 4; ++j) { o[j] = (f16)a[j]; o[4 + j] = (f16)b[j]; }
  *((f16x8*)(dst + (long long)m * DIMM * DIMM) + (long long)i) = o;
}

// ---------------- 256x256x32 NT GEMM, 1-barrier K-loop + counted vmcnt ----------------
// A [M x K], B [N x K] f16 row-major, C = A.B^T (+bias).
// 8 waves (2M x 4N), per-wave C = 128x64. 3-deep LDS ring (96 KiB).
// Per K-tile: stage t+2 (4 gload_lds) -> 12 ds_read_b128 -> 32 MFMA (compiler
// inserts fine-grained lgkmcnt -> intra-wave overlap) -> vmcnt(4) -> barrier.
// Invariant: at bottom of iter t, vmcnt(4) lands tile t+1 (its 4 loads are the
// oldest outstanding); barrier makes ALL waves' stages visible. Stage target
// slot (t+2)%3 was last read at iter t-1, protected by that barrier.
template<int NT, bool PROJ>
__global__ __launch_bounds__(512, 2) void gemm256(
    const f16* __restrict__ A, const f16* __restrict__ B,
    const float* __restrict__ b0, const float* __restrict__ b1, const float* __restrict__ b2,
    f16* __restrict__ o0, f16* __restrict__ o1, f16* __restrict__ o2,
    float* __restrict__ fo)
{
  constexpr int K  = DIMM;          // 1280
  constexpr int NT_TILES = K / 32;  // 40 K-tiles
  __shared__ __align__(16) f16 ldsA[3][8192];   // 3 bufs x 256 rows x 32 halfs
  __shared__ __align__(16) f16 ldsB[3][8192];

  const int tid  = threadIdx.x;
  const int lane = tid & 63;
  const int v    = tid >> 6;        // wave 0..7
  const int wm   = v >> 2;          // 0..1
  const int wn   = v & 3;           // 0..3
  const int l15  = lane & 15;
  const int g4   = lane >> 4;

  // block swizzle: XCD x owns tm in [8x,8x+8), tn-major within chunk (L2 ~7MB set)
  const int bid = blockIdx.x;
  const int xcd = bid & 7;
  const int j   = bid >> 3;
  const int tm  = xcd * 8 + (j & 7);
  const int tn  = j >> 3;

  // ---- staging addresses (pre-swizzled global source, linear LDS dest) ----
  const int r4    = lane >> 2;
  const int c_log = (lane & 3) ^ ((lane >> 3) & 3);
  const f16* gA0 = A + ((unsigned long long)(tm * 256 + v * 16 + r4)) * K + c_log * 8;
  const f16* gA1 = gA0 + (unsigned long long)128 * K;
  const f16* gB0 = B + ((unsigned long long)(tn * 256 + v * 16 + r4)) * K + c_log * 8;
  const f16* gB1 = gB0 + (unsigned long long)128 * K;
  f16* lA_ = &ldsA[0][v * 512 + lane * 8];
  f16* lB_ = &ldsB[0][v * 512 + lane * 8];

#define STAGE(b, kt) { async_load16(gA0 + (kt) * 32, lA_ + (b) * 8192);        \
                       async_load16(gA1 + (kt) * 32, lA_ + (b) * 8192 + 4096); \
                       async_load16(gB0 + (kt) * 32, lB_ + (b) * 8192);        \
                       async_load16(gB1 + (kt) * 32, lB_ + (b) * 8192 + 4096); }

  // ---- fragment read bases (slot is lane-constant across m/n) ----
  const int slot = g4 ^ ((l15 >> 1) & 3);
  const f16* rA = &ldsA[0][(wm * 128 + l15) * 32 + slot * 8];
  const f16* rB = &ldsB[0][(wn *  64 + l15) * 32 + slot * 8];

  f32x4 acc[8][4] = {};

  // ---- prologue: stage K-tiles 0,1 into bufs 0,1 ----
  STAGE(0, 0);
  STAGE(1, 1);
  asm volatile("s_waitcnt vmcnt(4)" ::: "memory");   // K-tile 0 landed (own wave)
  __builtin_amdgcn_sched_barrier(0);
  __builtin_amdgcn_s_barrier();                      // -> landed for all waves
  __builtin_amdgcn_sched_barrier(0);

  int buf = 0, sbuf = 2;
  for (int t = 0; t < NT_TILES; ++t) {
    if (t < NT_TILES - 2) STAGE(sbuf, t + 2);
    const f16* rAb = rA + buf * 8192;
    const f16* rBb = rB + buf * 8192;
    f16x8 af[8], bf[4];
    #pragma unroll
    for (int m = 0; m < 8; ++m) af[m] = *(const f16x8*)(rAb + m * 512);
    #pragma unroll
    for (int n = 0; n < 4; ++n) bf[n] = *(const f16x8*)(rBb + n * 512);
    __builtin_amdgcn_s_setprio(1);
    #pragma unroll
    for (int m = 0; m < 8; ++m)
      #pragma unroll
      for (int n = 0; n < 4; ++n)
        acc[m][n] = __builtin_amdgcn_mfma_f32_16x16x32_f16(af[m], bf[n], acc[m][n], 0, 0, 0);
    __builtin_amdgcn_s_setprio(0);
    // counted vmcnt: tile t+1's 4 loads are oldest outstanding -> land them.
    if (t < NT_TILES - 2) { asm volatile("s_waitcnt vmcnt(4)" ::: "memory"); }
    else                  { asm volatile("s_waitcnt vmcnt(0)" ::: "memory"); }
    __builtin_amdgcn_sched_barrier(0);   // nothing crosses into the unsynced window
    __builtin_amdgcn_s_barrier();
    __builtin_amdgcn_sched_barrier(0);
    buf  = (buf  == 2) ? 0 : buf  + 1;
    sbuf = (sbuf == 2) ? 0 : sbuf + 1;
  }
#undef STAGE

  // ---- epilogue: C row = g4*4+i (+m*16), col = l15 (+n*16) ----
  const int rowb = tm * 256 + wm * 128;
  if constexpr (PROJ) {
    const int colb = tn * 256 + wn * 64;
    #pragma unroll
    for (int n = 0; n < 4; ++n) {
      int c = colb + n * 16 + l15;
      float bb = b0[c];
      #pragma unroll
      for (int m = 0; m < 8; ++m)
        #pragma unroll
        for (int i = 0; i < 4; ++i) {
          int r = rowb + m * 16 + g4 * 4 + i;
          fo[(unsigned long long)r * DIMM + c] = acc[m][n][i] + bb;
        }
    }
  } else {
    const int seg  = tn / 5;                 // 0=Q 1=K 2=V (256-tile never straddles)
    const float* bias = seg == 0 ? b0 : (seg == 1 ? b1 : b2);
    f16* op = seg == 0 ? o0 : (seg == 1 ? o1 : o2);
    const int colb = (tn - seg * 5) * 256 + wn * 64;
    #pragma unroll
    for (int n = 0; n < 4; ++n) {
      int c = colb + n * 16 + l15;
      float bb = bias[c];
      #pragma unroll
      for (int m = 0; m < 8; ++m)
        #pragma unroll
        for (int i = 0; i < 4; ++i) {
          int r = rowb + m * 16 + g4 * 4 + i;
          op[(unsigned long long)r * DIMM + c] = (f16)(acc[m][n][i] + bb);
        }
    }
  }
}

// ---------------- RoPE in-place on fp16 Q,K ----------------
// thread owns pair {d0..d0+7, d0+40..d0+47} of one (s,h) -> race-free in-place
__global__ void rope_k(f16* __restrict__ Q, f16* __restrict__ K,
                       const float* __restrict__ cosp, const float* __restrict__ sinp)
{
  int t = blockIdx.x * 256 + threadIdx.x;  // S*16*5 threads
  int ch = t % 5;
  int h  = (t / 5) & (NHEAD - 1);
  int s  = t / 80;
  int d0 = ch * 8;
  unsigned long long base = (unsigned long long)s * DIMM + h * HDIM;
  const float* cp = cosp + (unsigned long long)s * HDIM;
  const float* sp = sinp + (unsigned long long)s * HDIM;
  f32x4 c0 = *(const f32x4*)&cp[d0],      c1 = *(const f32x4*)&cp[d0 + 4];
  f32x4 s0 = *(const f32x4*)&sp[d0],      s1 = *(const f32x4*)&sp[d0 + 4];
  f32x4 c2 = *(const f32x4*)&cp[40 + d0], c3 = *(const f32x4*)&cp[44 + d0];
  f32x4 s2 = *(const f32x4*)&sp[40 + d0], s3 = *(const f32x4*)&sp[44 + d0];
  f16x8 qlo = *(const f16x8*)&Q[base + d0];
  f16x8 qhi = *(const f16x8*)&Q[base + 40 + d0];
  f16x8 klo = *(const f16x8*)&K[base + d0];
  f16x8 khi = *(const f16x8*)&K[base + 40 + d0];
  f16x8 oql, oqh, okl, okh;
  #pragma unroll
  for (int jj = 0; jj < 8; ++jj) {
    float cl  = jj < 4 ? c0[jj] : c1[jj - 4];
    float sl  = jj < 4 ? s0[jj] : s1[jj - 4];
    float chh = jj < 4 ? c2[jj] : c3[jj - 4];
    float shh = jj < 4 ? s2[jj] : s3[jj - 4];
    float ql = (float)qlo[jj], qh = (float)qhi[jj];
    oql[jj] = (f16)(ql * cl - qh * sl);    // d<40:  x*cos - x[d+40]*sin
    oqh[jj] = (f16)(qh * chh + ql * shh);  // d>=40: x*cos + x[d-40]*sin
    float kl = (float)klo[jj], kh = (float)khi[jj];
    okl[jj] = (f16)(kl * cl - kh * sl);
    okh[jj] = (f16)(kh * chh + kl * shh);
  }
  *(f16x8*)&Q[base + d0]      = oql;
  *(f16x8*)&Q[base + 40 + d0] = oqh;
  *(f16x8*)&K[base + d0]      = okl;
  *(f16x8*)&K[base + 40 + d0] = okh;
}

// ---------------- windowed attention: one block per (head, window) ----------------
__global__ __launch_bounds__(256) void attn_k(const f16* __restrict__ Qb, const f16* __restrict__ Kb,
                                              const f16* __restrict__ Vb, f16* __restrict__ AO)
{
  // Q/K: 64 rows x 128 halfs (cols 80..95 zero-pad, 96..127 swizzle slack)
  // 16B-chunk XOR swizzle (chunk ^ row&7) -> conflict-free ds_read_b128
  __shared__ __align__(16) f16 Qs[64 * 128];
  __shared__ __align__(16) f16 Ks[64 * 128];
  __shared__ __align__(16) f16 Vt[80 * 64];   // V transposed: Vt[d][k], swizzled
  __shared__ __align__(16) f16 Ps[64 * 64];   // softmax probs, swizzled

  const int tid = threadIdx.x, lane = tid & 63, wv = tid >> 6;
  const int l15 = lane & 15, g4 = lane >> 4;
  const int b = blockIdx.x;
  const int h = b & (NHEAD - 1);
  const int w = b >> 4;
  const unsigned long long gbase = (unsigned long long)w * WIN * DIMM + h * HDIM;

  for (int c = tid; c < 64 * 12; c += 256) {
    int row = c / 12, ch = c % 12;
    f16x8 qv = {}, kv = {};
    if (ch < 10) {
      unsigned long long g = gbase + (unsigned long long)row * DIMM + (ch << 3);
      qv = *(const f16x8*)&Qb[g];
      kv = *(const f16x8*)&Kb[g];
    }
    int dst = row * 128 + ((ch ^ (row & 7)) << 3);
    *(f16x8*)&Qs[dst] = qv;
    *(f16x8*)&Ks[dst] = kv;
  }
  for (int c = tid; c < 640; c += 256) {
    int r = c / 10, ch = c % 10;  // r = k index, d = ch*8+j
    f16x8 vv = *(const f16x8*)&Vb[gbase + (unsigned long long)r * DIMM + (ch << 3)];
    #pragma unroll
    for (int jj = 0; jj < 8; ++jj) {
      int d = (ch << 3) + jj;
      Vt[d * 64 + (((r >> 3) ^ (d & 7)) << 3) + (r & 7)] = vv[jj];
    }
  }
  __syncthreads();

  // QK^T: wave strip = C rows [16wv,16wv+16), cols 0..63; K padded to 96
  f32x4 acc[4] = {};
  const int arow = wv * 16 + l15;
  #pragma unroll
  for (int ks = 0; ks < 3; ++ks) {
    int chA = (ks << 2) + g4;
    f16x8 af = *(const f16x8*)&Qs[arow * 128 + ((chA ^ (arow & 7)) << 3)];
    #pragma unroll
    for (int n = 0; n < 4; ++n) {
      int brow = n * 16 + l15;
      f16x8 bf = *(const f16x8*)&Ks[brow * 128 + ((chA ^ (brow & 7)) << 3)];
      acc[n] = __builtin_amdgcn_mfma_f32_16x16x32_f16(af, bf, acc[n], 0, 0, 0);
    }
  }

  // wave-parallel softmax: row = 16wv + 4*g4 + i; lane holds cols 16n + l15
  const float scl2 = 0.1118033988749895f * 1.4426950408889634f;  // (1/sqrt(80))*log2(e)
  #pragma unroll
  for (int i = 0; i < 4; ++i) {
    float mx = fmaxf(fmaxf(acc[0][i], acc[1][i]), fmaxf(acc[2][i], acc[3][i]));
    mx = fmaxf(mx, __shfl_xor(mx, 1));
    mx = fmaxf(mx, __shfl_xor(mx, 2));
    mx = fmaxf(mx, __shfl_xor(mx, 4));
    mx = fmaxf(mx, __shfl_xor(mx, 8));
    float pr[4];
    float sm = 0.f;
    #pragma unroll
    for (int n = 0; n < 4; ++n) { pr[n] = exp2f((acc[n][i] - mx) * scl2); sm += pr[n]; }
    sm += __shfl_xor(sm, 1);
    sm += __shfl_xor(sm, 2);
    sm += __shfl_xor(sm, 4);
    sm += __shfl_xor(sm, 8);
    float rinv = 1.0f / sm;
    int row = wv * 16 + g4 * 4 + i;
    int rb = row * 64, rx = row & 7;
    #pragma unroll
    for (int n = 0; n < 4; ++n) {
      int col = n * 16 + l15;
      Ps[rb + (((col >> 3) ^ rx) << 3) + (col & 7)] = (f16)(pr[n] * rinv);
    }
  }
  // no barrier: each wave reads back only the 16 Ps rows it wrote

  // PV: out strip rows [16wv,16wv+16), d = 0..79, contraction k = 0..63
  f32x4 o[5] = {};
  #pragma unroll
  for (int ks = 0; ks < 2; ++ks) {
    int chP = (ks << 2) + g4;
    int prow = wv * 16 + l15;
    f16x8 pf = *(const f16x8*)&Ps[prow * 64 + ((chP ^ (prow & 7)) << 3)];
    #pragma unroll
    for (int n = 0; n < 5; ++n) {
      int drow = n * 16 + l15;
      f16x8 vf = *(const f16x8*)&Vt[drow * 64 + ((chP ^ (drow & 7)) << 3)];
      o[n] = __builtin_amdgcn_mfma_f32_16x16x32_f16(pf, vf, o[n], 0, 0, 0);
    }
  }
  #pragma unroll
  for (int n = 0; n < 5; ++n)
    #pragma unroll
    for (int i = 0; i < 4; ++i) {
      int q = wv * 16 + g4 * 4 + i;
      int d = n * 16 + l15;
      AO[(unsigned long long)(w * WIN + q) * DIMM + h * HDIM + d] = (f16)o[n][i];
    }
}

// ---------------- host launcher ----------------
extern "C" void kernel_launch(void* const* d_in, const int* in_sizes, int n_in,
                              void* d_out, int out_size, void* d_ws, size_t ws_size,
                              hipStream_t stream)
{
  const float* H    = (const float*)d_in[0];
  const float* cosp = (const float*)d_in[1];
  const float* sinp = (const float*)d_in[2];
  const float* Wq   = (const float*)d_in[3];
  const float* bq   = (const float*)d_in[4];
  const float* Wk   = (const float*)d_in[5];
  const float* bk   = (const float*)d_in[6];
  const float* Wv   = (const float*)d_in[7];
  const float* bv   = (const float*)d_in[8];
  const float* Wp   = (const float*)d_in[9];
  const float* bp   = (const float*)d_in[10];
  float* out = (float*)d_out;

  char* ws = (char*)d_ws;
  f16* Hb   = (f16*)(ws + OFF_HB);
  f16* Wqkv = (f16*)(ws + OFF_WQKV);
  f16* Wpb  = (f16*)(ws + OFF_WP);
  f16* Qb   = (f16*)(ws + OFF_Q);
  f16* Kb   = (f16*)(ws + OFF_K);
  f16* Vb   = (f16*)(ws + OFF_V);
  f16* AO   = (f16*)(ws + OFF_AO);

  const int nH8 = S_LEN * DIMM / 8;
  const int nW8 = DIMM * DIMM / 8;
  cvt_k<<<nH8 / 256, 256, 0, stream>>>(H, Hb, nH8);
  cvtw_k<<<dim3(nW8 / 256, 4), 256, 0, stream>>>(Wq, Wk, Wv, Wp, Wqkv);

  gemm256<15, false><<<8 * 15 * 8, 512, 0, stream>>>(Hb, Wqkv, bq, bk, bv, Qb, Kb, Vb, nullptr);
  rope_k<<<S_LEN * 80 / 256, 256, 0, stream>>>(Qb, Kb, cosp, sinp);
  attn_k<<<NHEAD * (S_LEN / WIN), 256, 0, stream>>>(Qb, Kb, Vb, AO);
  gemm256<5, true><<<8 * 5 * 8, 512, 0, stream>>>(AO, Wpb, bp, nullptr, nullptr,
                                                  nullptr, nullptr, nullptr, out);
}

// Round 5
// 523.990 us; speedup vs baseline: 1.1657x; 1.1657x over previous
//
#include <hip/hip_runtime.h>
#include <hip/hip_fp16.h>

typedef _Float16 f16;
typedef _Float16 f16x8 __attribute__((ext_vector_type(8)));
typedef float f32x4 __attribute__((ext_vector_type(4)));

#define S_LEN 16384
#define DIMM  1280
#define NHEAD 16
#define HDIM  80
#define WIN   64

// ---- workspace layout (bytes) ----
#define OFF_HB   0ULL
#define OFF_WQKV (OFF_HB   + (unsigned long long)S_LEN*DIMM*2)
#define OFF_WP   (OFF_WQKV + (unsigned long long)3*DIMM*DIMM*2)
#define OFF_Q    (OFF_WP   + (unsigned long long)DIMM*DIMM*2)
#define OFF_K    (OFF_Q    + (unsigned long long)S_LEN*DIMM*2)
#define OFF_V    (OFF_K    + (unsigned long long)S_LEN*DIMM*2)
#define OFF_AO   OFF_HB    // aliases Hb (stream-ordered: Hb last read by QKV GEMM)

static __device__ __forceinline__ void async_load16(const f16* g, f16* lds) {
  __builtin_amdgcn_global_load_lds((const __attribute__((address_space(1))) void*)g,
                                   (__attribute__((address_space(3))) void*)lds,
                                   16, 0, 0);
}

// ---------------- fp32 -> fp16 converts ----------------
__global__ void cvt_k(const float* __restrict__ src, f16* __restrict__ dst, int n8) {
  int i = blockIdx.x * 256 + threadIdx.x;
  if (i >= n8) return;
  const f32x4* s = (const f32x4*)src + 2 * (long long)i;
  f32x4 a = s[0], b = s[1];
  f16x8 o;
  #pragma unroll
  for (int j = 0; j < 4; ++j) { o[j] = (f16)a[j]; o[4 + j] = (f16)b[j]; }
  *((f16x8*)dst + (long long)i) = o;
}

__global__ void cvtw_k(const float* __restrict__ w0, const float* __restrict__ w1,
                       const float* __restrict__ w2, const float* __restrict__ w3,
                       f16* __restrict__ dst) {
  int m = blockIdx.y;
  const float* src = m == 0 ? w0 : m == 1 ? w1 : m == 2 ? w2 : w3;
  int i = blockIdx.x * 256 + threadIdx.x;
  const f32x4* s = (const f32x4*)src + 2 * (long long)i;
  f32x4 a = s[0], b = s[1];
  f16x8 o;
  #pragma unroll
  for (int j = 0; j < 4; ++j) { o[j] = (f16)a[j]; o[4 + j] = (f16)b[j]; }
  *((f16x8*)(dst + (long long)m * DIMM * DIMM) + (long long)i) = o;
}

// ---------------- 256x128x32 NT GEMM, 2 blocks/CU ----------------
// A [M x K], B [N x K] f16 row-major, C = A.B^T (+bias). NT = #128-col tiles.
// 8 waves (4M x 2N), per-wave C = 64x64 (m97's verified per-wave shape).
// 3-ring LDS = 72 KiB -> 2 blocks/CU: cross-block overlap covers the per-tile
// vmcnt+barrier drain (the round-4 regression at 1 block/CU lacked this).
// Per K-tile: stage t+2 (3 gload_lds) -> 8 ds_read_b128 -> 16 MFMA ->
// vmcnt(3) -> barrier.  Ring invariant: at bottom of iter t, the oldest 3
// outstanding loads are tile t+1's -> vmcnt(3) lands them; barrier publishes.
template<int NT, bool PROJ>
__global__ __launch_bounds__(512, 4) void gemm256(
    const f16* __restrict__ A, const f16* __restrict__ B,
    const float* __restrict__ b0, const float* __restrict__ b1, const float* __restrict__ b2,
    f16* __restrict__ o0, f16* __restrict__ o1, f16* __restrict__ o2,
    float* __restrict__ fo)
{
  constexpr int K  = DIMM;          // 1280
  constexpr int NT_TILES = K / 32;  // 40 K-tiles
  __shared__ __align__(16) f16 ldsA[3][8192];   // 3 bufs x 256 rows x 32 halfs
  __shared__ __align__(16) f16 ldsB[3][4096];   // 3 bufs x 128 rows x 32 halfs

  const int tid  = threadIdx.x;
  const int lane = tid & 63;
  const int v    = tid >> 6;        // wave 0..7
  const int wm   = v >> 1;          // 0..3
  const int wn   = v & 1;           // 0..1
  const int l15  = lane & 15;
  const int g4   = lane >> 4;

  // block swizzle: XCD x owns tm in [8x,8x+8) (A-panel ~5MB/XCD), tn-major
  const int bid = blockIdx.x;
  const int xcd = bid & 7;
  const int j   = bid >> 3;
  const int tm  = xcd * 8 + (j & 7);
  const int tn  = j >> 3;

  // ---- staging addresses (pre-swizzled global source, linear LDS dest) ----
  // physical chunk p=lane&3 holds logical chunk p ^ ((r4>>1)&3)  (r4 = row in 16-grp)
  const int r4    = lane >> 2;
  const int c_log = (lane & 3) ^ ((lane >> 3) & 3);
  const f16* gA0 = A + ((unsigned long long)(tm * 256 + v * 16 + r4)) * K + c_log * 8;
  const f16* gA1 = gA0 + (unsigned long long)128 * K;
  const f16* gB0 = B + ((unsigned long long)(tn * 128 + v * 16 + r4)) * K + c_log * 8;
  f16* lA_ = &ldsA[0][v * 512 + lane * 8];
  f16* lB_ = &ldsB[0][v * 512 + lane * 8];

#define STAGE(b, kt) { async_load16(gA0 + (kt) * 32, lA_ + (b) * 8192);        \
                       async_load16(gA1 + (kt) * 32, lA_ + (b) * 8192 + 4096); \
                       async_load16(gB0 + (kt) * 32, lB_ + (b) * 4096); }

  // ---- fragment read bases: row l15 in 16-grp -> physical slot g4^((l15>>1)&3) ----
  const int slot = g4 ^ ((l15 >> 1) & 3);
  const f16* rA = &ldsA[0][(wm * 64 + l15) * 32 + slot * 8];   // + m*512 + buf*8192
  const f16* rB = &ldsB[0][(wn * 64 + l15) * 32 + slot * 8];   // + n*512 + buf*4096

  f32x4 acc[4][4] = {};

  // ---- prologue: stage K-tiles 0,1 into bufs 0,1 ----
  STAGE(0, 0);
  STAGE(1, 1);
  asm volatile("s_waitcnt vmcnt(3)" ::: "memory");   // tile 0 (oldest 3) landed
  __builtin_amdgcn_sched_barrier(0);
  __builtin_amdgcn_s_barrier();
  __builtin_amdgcn_sched_barrier(0);

  int buf = 0, sbuf = 2;
  for (int t = 0; t < NT_TILES; ++t) {
    if (t < NT_TILES - 2) STAGE(sbuf, t + 2);
    const f16* rAb = rA + buf * 8192;
    const f16* rBb = rB + buf * 4096;
    f16x8 af[4], bf[4];
    #pragma unroll
    for (int m = 0; m < 4; ++m) af[m] = *(const f16x8*)(rAb + m * 512);
    #pragma unroll
    for (int n = 0; n < 4; ++n) bf[n] = *(const f16x8*)(rBb + n * 512);
    #pragma unroll
    for (int m = 0; m < 4; ++m)
      #pragma unroll
      for (int n = 0; n < 4; ++n)
        acc[m][n] = __builtin_amdgcn_mfma_f32_16x16x32_f16(af[m], bf[n], acc[m][n], 0, 0, 0);
    if (t < NT_TILES - 2) { asm volatile("s_waitcnt vmcnt(3)" ::: "memory"); }
    else                  { asm volatile("s_waitcnt vmcnt(0)" ::: "memory"); }
    __builtin_amdgcn_sched_barrier(0);
    __builtin_amdgcn_s_barrier();
    __builtin_amdgcn_sched_barrier(0);
    buf  = (buf  == 2) ? 0 : buf  + 1;
    sbuf = (sbuf == 2) ? 0 : sbuf + 1;
  }
#undef STAGE

  // ---- epilogue: C row = g4*4+i (+m*16), col = l15 (+n*16) ----
  const int rowb = tm * 256 + wm * 64;
  if constexpr (PROJ) {
    const int colb = tn * 128 + wn * 64;
    #pragma unroll
    for (int n = 0; n < 4; ++n) {
      int c = colb + n * 16 + l15;
      float bb = b0[c];
      #pragma unroll
      for (int m = 0; m < 4; ++m)
        #pragma unroll
        for (int i = 0; i < 4; ++i) {
          int r = rowb + m * 16 + g4 * 4 + i;
          fo[(unsigned long long)r * DIMM + c] = acc[m][n][i] + bb;
        }
    }
  } else {
    const int seg  = tn / 10;                // 0=Q 1=K 2=V (128-tile never straddles)
    const float* bias = seg == 0 ? b0 : (seg == 1 ? b1 : b2);
    f16* op = seg == 0 ? o0 : (seg == 1 ? o1 : o2);
    const int colb = (tn - seg * 10) * 128 + wn * 64;
    #pragma unroll
    for (int n = 0; n < 4; ++n) {
      int c = colb + n * 16 + l15;
      float bb = bias[c];
      #pragma unroll
      for (int m = 0; m < 4; ++m)
        #pragma unroll
        for (int i = 0; i < 4; ++i) {
          int r = rowb + m * 16 + g4 * 4 + i;
          op[(unsigned long long)r * DIMM + c] = (f16)(acc[m][n][i] + bb);
        }
    }
  }
}

// ---------------- windowed attention with fused RoPE (round-2 verbatim, measured in 530) ----------------
__global__ __launch_bounds__(256) void attn_k(const f16* __restrict__ Qb, const f16* __restrict__ Kb,
                                              const f16* __restrict__ Vb,
                                              const float* __restrict__ cosp, const float* __restrict__ sinp,
                                              f16* __restrict__ AO)
{
  __shared__ __align__(16) f16 Qs[64 * 128];
  __shared__ __align__(16) f16 Ks[64 * 128];
  __shared__ __align__(16) f16 Vt[80 * 64];
  __shared__ __align__(16) f16 Ps[64 * 64];

  const int tid = threadIdx.x, lane = tid & 63, wv = tid >> 6;
  const int l15 = lane & 15, g4 = lane >> 4;
  const int b = blockIdx.x;
  const int h = b & (NHEAD - 1);
  const int w = b >> 4;
  const unsigned long long gbase = (unsigned long long)w * WIN * DIMM + h * HDIM;

  for (int c = tid; c < 320; c += 256) {
    int row = c / 5, ch = c % 5;
    int d0 = ch << 3;
    unsigned long long g = gbase + (unsigned long long)row * DIMM;
    const float* cp = cosp + (unsigned long long)(w * WIN + row) * HDIM;
    const float* sp = sinp + (unsigned long long)(w * WIN + row) * HDIM;
    f16x8 ql = *(const f16x8*)&Qb[g + d0];
    f16x8 qh = *(const f16x8*)&Qb[g + 40 + d0];
    f16x8 kl = *(const f16x8*)&Kb[g + d0];
    f16x8 kh = *(const f16x8*)&Kb[g + 40 + d0];
    f16x8 oql, oqh, okl, okh;
    #pragma unroll
    for (int jj = 0; jj < 8; ++jj) {
      float cl = cp[d0 + jj],      sl = sp[d0 + jj];
      float chh = cp[40 + d0 + jj], shh = sp[40 + d0 + jj];
      float qlo = (float)ql[jj], qhi = (float)qh[jj];
      oql[jj] = (f16)(qlo * cl - qhi * sl);
      oqh[jj] = (f16)(qhi * chh + qlo * shh);
      float klo = (float)kl[jj], khi = (float)kh[jj];
      okl[jj] = (f16)(klo * cl - khi * sl);
      okh[jj] = (f16)(khi * chh + klo * shh);
    }
    int rx = row & 7, rb = row * 128;
    *(f16x8*)&Qs[rb + ((ch ^ rx) << 3)]       = oql;
    *(f16x8*)&Qs[rb + (((ch + 5) ^ rx) << 3)] = oqh;
    *(f16x8*)&Ks[rb + ((ch ^ rx) << 3)]       = okl;
    *(f16x8*)&Ks[rb + (((ch + 5) ^ rx) << 3)] = okh;
  }
  for (int c = tid; c < 128; c += 256) {
    int row = c >> 1, ch = 10 + (c & 1);
    f16x8 z = {};
    int off = row * 128 + ((ch ^ (row & 7)) << 3);
    *(f16x8*)&Qs[off] = z;
    *(f16x8*)&Ks[off] = z;
  }
  for (int c = tid; c < 640; c += 256) {
    int r = c / 10, ch = c % 10;
    f16x8 vv = *(const f16x8*)&Vb[gbase + (unsigned long long)r * DIMM + (ch << 3)];
    #pragma unroll
    for (int jj = 0; jj < 8; ++jj) {
      int d = (ch << 3) + jj;
      Vt[d * 64 + (((r >> 3) ^ (d & 7)) << 3) + (r & 7)] = vv[jj];
    }
  }
  __syncthreads();

  f32x4 acc[4] = {};
  const int arow = wv * 16 + l15;
  #pragma unroll
  for (int ks = 0; ks < 3; ++ks) {
    int chA = (ks << 2) + g4;
    f16x8 af = *(const f16x8*)&Qs[arow * 128 + ((chA ^ (arow & 7)) << 3)];
    #pragma unroll
    for (int n = 0; n < 4; ++n) {
      int brow = n * 16 + l15;
      f16x8 bf = *(const f16x8*)&Ks[brow * 128 + ((chA ^ (brow & 7)) << 3)];
      acc[n] = __builtin_amdgcn_mfma_f32_16x16x32_f16(af, bf, acc[n], 0, 0, 0);
    }
  }

  const float scl2 = 0.1118033988749895f * 1.4426950408889634f;  // (1/sqrt(80))*log2(e)
  #pragma unroll
  for (int i = 0; i < 4; ++i) {
    float mx = fmaxf(fmaxf(acc[0][i], acc[1][i]), fmaxf(acc[2][i], acc[3][i]));
    mx = fmaxf(mx, __shfl_xor(mx, 1));
    mx = fmaxf(mx, __shfl_xor(mx, 2));
    mx = fmaxf(mx, __shfl_xor(mx, 4));
    mx = fmaxf(mx, __shfl_xor(mx, 8));
    float pr[4];
    float sm = 0.f;
    #pragma unroll
    for (int n = 0; n < 4; ++n) { pr[n] = exp2f((acc[n][i] - mx) * scl2); sm += pr[n]; }
    sm += __shfl_xor(sm, 1);
    sm += __shfl_xor(sm, 2);
    sm += __shfl_xor(sm, 4);
    sm += __shfl_xor(sm, 8);
    float rinv = 1.0f / sm;
    int row = wv * 16 + g4 * 4 + i;
    int rb = row * 64, rx = row & 7;
    #pragma unroll
    for (int n = 0; n < 4; ++n) {
      int col = n * 16 + l15;
      Ps[rb + (((col >> 3) ^ rx) << 3) + (col & 7)] = (f16)(pr[n] * rinv);
    }
  }
  // no barrier: each wave reads back only the 16 Ps rows it wrote (DS in-order per wave)

  f32x4 o[5] = {};
  #pragma unroll
  for (int ks = 0; ks < 2; ++ks) {
    int chP = (ks << 2) + g4;
    int prow = wv * 16 + l15;
    f16x8 pf = *(const f16x8*)&Ps[prow * 64 + ((chP ^ (prow & 7)) << 3)];
    #pragma unroll
    for (int n = 0; n < 5; ++n) {
      int drow = n * 16 + l15;
      f16x8 vf = *(const f16x8*)&Vt[drow * 64 + ((chP ^ (drow & 7)) << 3)];
      o[n] = __builtin_amdgcn_mfma_f32_16x16x32_f16(pf, vf, o[n], 0, 0, 0);
    }
  }
  #pragma unroll
  for (int n = 0; n < 5; ++n)
    #pragma unroll
    for (int i = 0; i < 4; ++i) {
      int q = wv * 16 + g4 * 4 + i;
      int d = n * 16 + l15;
      AO[(unsigned long long)(w * WIN + q) * DIMM + h * HDIM + d] = (f16)o[n][i];
    }
}

// ---------------- host launcher ----------------
extern "C" void kernel_launch(void* const* d_in, const int* in_sizes, int n_in,
                              void* d_out, int out_size, void* d_ws, size_t ws_size,
                              hipStream_t stream)
{
  const float* H    = (const float*)d_in[0];
  const float* cosp = (const float*)d_in[1];
  const float* sinp = (const float*)d_in[2];
  const float* Wq   = (const float*)d_in[3];
  const float* bq   = (const float*)d_in[4];
  const float* Wk   = (const float*)d_in[5];
  const float* bk   = (const float*)d_in[6];
  const float* Wv   = (const float*)d_in[7];
  const float* bv   = (const float*)d_in[8];
  const float* Wp   = (const float*)d_in[9];
  const float* bp   = (const float*)d_in[10];
  float* out = (float*)d_out;

  char* ws = (char*)d_ws;
  f16* Hb   = (f16*)(ws + OFF_HB);
  f16* Wqkv = (f16*)(ws + OFF_WQKV);
  f16* Wpb  = (f16*)(ws + OFF_WP);
  f16* Qb   = (f16*)(ws + OFF_Q);
  f16* Kb   = (f16*)(ws + OFF_K);
  f16* Vb   = (f16*)(ws + OFF_V);
  f16* AO   = (f16*)(ws + OFF_AO);

  const int nH8 = S_LEN * DIMM / 8;
  const int nW8 = DIMM * DIMM / 8;
  cvt_k<<<nH8 / 256, 256, 0, stream>>>(H, Hb, nH8);
  cvtw_k<<<dim3(nW8 / 256, 4), 256, 0, stream>>>(Wq, Wk, Wv, Wp, Wqkv);

  gemm256<30, false><<<8 * 30 * 8, 512, 0, stream>>>(Hb, Wqkv, bq, bk, bv, Qb, Kb, Vb, nullptr);
  attn_k<<<NHEAD * (S_LEN / WIN), 256, 0, stream>>>(Qb, Kb, Vb, cosp, sinp, AO);
  gemm256<10, true><<<8 * 10 * 8, 512, 0, stream>>>(AO, Wpb, bp, nullptr, nullptr,
                                                    nullptr, nullptr, nullptr, out);
}